// Round 5
// baseline (4725.466 us; speedup 1.0000x reference)
//
#include <hip/hip_runtime.h>

#define N_NODES 100000
#define N_EDGES 3200000
#define D 256
#define RPB 8                            // rows per bucket
#define NBUCKET (N_NODES / RPB)          // 12500
#define GEMM_TILES (N_NODES / 32)        // 3125 tiles of 32 rows
#define GEMM_BLOCKS ((GEMM_TILES + 3) / 4)  // 782
#define HIST_BLOCKS (N_EDGES / 256)      // 12500
#define ZERO_BLOCKS ((NBUCKET + 255) / 256) // 49
#define WSH_BLOCKS 32

using u16 = unsigned short;
using u32 = unsigned int;

typedef __attribute__((ext_vector_type(8))) short bf16x8;
typedef __attribute__((ext_vector_type(4))) float f32x4;

__device__ inline u16 f2bf(float f) {
    u32 x = __builtin_bit_cast(u32, f);
    return (u16)((x + 0x7FFFu + ((x >> 16) & 1u)) >> 16);
}
__device__ inline float bf2f(u16 u) {
    return __builtin_bit_cast(float, (u32)u << 16);
}

// -------- prep: zero bucket counters + W -> bf16 B-fragment layout ---------
// Wf layout [kt(8)][nt(16)][lane(64)][j(8)]:
//   b[j] = W[kt*32 + (lane>>4)*8 + j][nt*16 + (lane&15)]
__global__ __launch_bounds__(256) void prep_kernel(
    const float* __restrict__ W, u16* __restrict__ Wf, int* __restrict__ cnt)
{
    if (blockIdx.x < ZERO_BLOCKS) {
        const int i = blockIdx.x * 256 + threadIdx.x;
        if (i < NBUCKET) cnt[i] = 0;
        return;
    }
    const int t = (blockIdx.x - ZERO_BLOCKS) * 256 + threadIdx.x;  // 0..8191
    const int kt = t >> 10;
    const int nt = (t >> 6) & 15;
    const int lane = t & 63;
    const int kbase = kt * 32 + ((lane >> 4) * 8);
    const int n = nt * 16 + (lane & 15);
    u16 frag[8];
    #pragma unroll
    for (int j = 0; j < 8; ++j)
        frag[j] = f2bf(W[(size_t)(kbase + j) * D + n]);
    #pragma unroll
    for (int j = 0; j < 8; ++j)
        Wf[(size_t)t * 8 + j] = frag[j];
}

// -------- fused: GEMM (blocks < GEMM_BLOCKS) + bucket histogram (rest) -----
__global__ __launch_bounds__(256) void gemm_hist_kernel(
    const float* __restrict__ X, const u16* __restrict__ Wf,
    u16* __restrict__ S, const int* __restrict__ row, int* __restrict__ cnt)
{
    if (blockIdx.x >= GEMM_BLOCKS) {
        const int e = (blockIdx.x - GEMM_BLOCKS) * 256 + threadIdx.x;
        atomicAdd(&cnt[row[e] >> 3], 1);
        return;
    }
    const int lane = threadIdx.x & 63;
    const int tile = blockIdx.x * 4 + (threadIdx.x >> 6);
    if (tile >= GEMM_TILES) return;
    const int row0 = tile * 32;
    const int m = lane & 15;
    const int quad = lane >> 4;

    f32x4 acc0[16], acc1[16];
    #pragma unroll
    for (int t = 0; t < 16; ++t) {
        acc0[t] = (f32x4){0.f, 0.f, 0.f, 0.f};
        acc1[t] = (f32x4){0.f, 0.f, 0.f, 0.f};
    }

    const float* xA = X + (size_t)(row0 + m) * D + quad * 8;
    const float* xB = X + (size_t)(row0 + 16 + m) * D + quad * 8;
    const bf16x8* __restrict__ Bf = (const bf16x8*)Wf;

    for (int k0 = 0; k0 < 8; ++k0) {               // K-step = 32
        const float4 a0l = *(const float4*)(xA + k0 * 32);
        const float4 a0h = *(const float4*)(xA + k0 * 32 + 4);
        const float4 a1l = *(const float4*)(xB + k0 * 32);
        const float4 a1h = *(const float4*)(xB + k0 * 32 + 4);
        bf16x8 a0, a1;
        a0[0] = (short)f2bf(a0l.x); a0[1] = (short)f2bf(a0l.y);
        a0[2] = (short)f2bf(a0l.z); a0[3] = (short)f2bf(a0l.w);
        a0[4] = (short)f2bf(a0h.x); a0[5] = (short)f2bf(a0h.y);
        a0[6] = (short)f2bf(a0h.z); a0[7] = (short)f2bf(a0h.w);
        a1[0] = (short)f2bf(a1l.x); a1[1] = (short)f2bf(a1l.y);
        a1[2] = (short)f2bf(a1l.z); a1[3] = (short)f2bf(a1l.w);
        a1[4] = (short)f2bf(a1h.x); a1[5] = (short)f2bf(a1h.y);
        a1[6] = (short)f2bf(a1h.z); a1[7] = (short)f2bf(a1h.w);

        const bf16x8* bp = Bf + (size_t)k0 * 1024 + lane;
        #pragma unroll
        for (int g = 0; g < 4; ++g) {
            const bf16x8 b0 = bp[g * 256 + 0];
            const bf16x8 b1 = bp[g * 256 + 64];
            const bf16x8 b2 = bp[g * 256 + 128];
            const bf16x8 b3 = bp[g * 256 + 192];
            acc0[g*4+0] = __builtin_amdgcn_mfma_f32_16x16x32_bf16(a0, b0, acc0[g*4+0], 0, 0, 0);
            acc1[g*4+0] = __builtin_amdgcn_mfma_f32_16x16x32_bf16(a1, b0, acc1[g*4+0], 0, 0, 0);
            acc0[g*4+1] = __builtin_amdgcn_mfma_f32_16x16x32_bf16(a0, b1, acc0[g*4+1], 0, 0, 0);
            acc1[g*4+1] = __builtin_amdgcn_mfma_f32_16x16x32_bf16(a1, b1, acc1[g*4+1], 0, 0, 0);
            acc0[g*4+2] = __builtin_amdgcn_mfma_f32_16x16x32_bf16(a0, b2, acc0[g*4+2], 0, 0, 0);
            acc1[g*4+2] = __builtin_amdgcn_mfma_f32_16x16x32_bf16(a1, b2, acc1[g*4+2], 0, 0, 0);
            acc0[g*4+3] = __builtin_amdgcn_mfma_f32_16x16x32_bf16(a0, b3, acc0[g*4+3], 0, 0, 0);
            acc1[g*4+3] = __builtin_amdgcn_mfma_f32_16x16x32_bf16(a1, b3, acc1[g*4+3], 0, 0, 0);
        }
    }

    #pragma unroll
    for (int nt = 0; nt < 16; ++nt) {
        #pragma unroll
        for (int i = 0; i < 4; ++i) {
            S[(size_t)(row0 + quad * 4 + i) * D + nt * 16 + m]      = f2bf(acc0[nt][i]);
            S[(size_t)(row0 + 16 + quad * 4 + i) * D + nt * 16 + m] = f2bf(acc1[nt][i]);
        }
    }
}

// -------- single-block scan over 12500 bucket counts -----------------------
__global__ __launch_bounds__(1024) void bucketscan_kernel(
    int* __restrict__ cnt, int* __restrict__ starts)
{
    __shared__ int wsum[16];
    __shared__ int carry;
    const int tid = threadIdx.x, lane = tid & 63, wv = tid >> 6;
    if (tid == 0) carry = 0;
    __syncthreads();
    for (int base = 0; base < NBUCKET; base += 1024) {
        const int i = base + tid;
        const int c = (i < NBUCKET) ? cnt[i] : 0;
        int x = c;
        #pragma unroll
        for (int off = 1; off < 64; off <<= 1) {
            int y = __shfl_up(x, off);
            if (lane >= off) x += y;
        }
        if (lane == 63) wsum[wv] = x;
        __syncthreads();
        if (tid == 0) {
            int run = carry;
            #pragma unroll
            for (int w = 0; w < 16; ++w) { int t = wsum[w]; wsum[w] = run; run += t; }
            carry = run;
        }
        __syncthreads();
        const int excl = x - c + wsum[wv];
        if (i < NBUCKET) { starts[i] = excl; cnt[i] = excl; }   // cnt := cursor
        __syncthreads();
    }
    if (tid == 0) starts[NBUCKET] = N_EDGES;
}

// -------- placement: scatter {rlow|col, val} into bucket segments ----------
__global__ __launch_bounds__(256) void place_kernel(
    const int* __restrict__ row, const int* __restrict__ col,
    const float* __restrict__ val, int* __restrict__ cursor,
    uint2* __restrict__ pce)
{
    const int e = blockIdx.x * 256 + threadIdx.x;
    const int r = row[e];
    const u32 key = ((u32)(r & 7) << 17) | (u32)col[e];
    const float v = val[e];
    const int pos = atomicAdd(&cursor[r >> 3], 1);
    pce[pos] = make_uint2(key, __builtin_bit_cast(u32, v));
}

// -------- reduce: block per bucket, 8x256 fp32 LDS accumulator -------------
// Lane owns stride-64 columns -> ds_add_f32 banks = lane%32 (conflict-free).
__global__ __launch_bounds__(256) void reduce_kernel(
    const u16* __restrict__ S, const int* __restrict__ starts,
    const uint2* __restrict__ pce, const float* __restrict__ bias,
    float* __restrict__ out)
{
    __shared__ float accum[RPB * D];   // 8 KB
    const int tid = threadIdx.x;
    const int lane = tid & 63;
    const int wv = tid >> 6;
    const int bkt = blockIdx.x;

    float4* a4 = (float4*)accum;
    #pragma unroll
    for (int i = 0; i < RPB * D / 4 / 256; ++i)
        a4[i * 256 + tid] = make_float4(0.f, 0.f, 0.f, 0.f);
    __syncthreads();

    const int s0 = starts[bkt], s1 = starts[bkt + 1];

    for (int base = s0 + wv * 64; base < s1; base += 256) {
        const int n = min(64, s1 - base);
        uint2 pr = make_uint2(0u, 0u);
        if (lane < n) pr = pce[base + lane];
        const u32 key = pr.x;
        const float v = __builtin_bit_cast(float, pr.y);

        int j = 0;
        for (; j + 4 <= n; j += 4) {
            u32 k[4]; float vv[4];
            #pragma unroll
            for (int u = 0; u < 4; ++u) {
                k[u] = __shfl(key, j + u);
                vv[u] = __shfl(v, j + u);
            }
            u16 sv[4][4];
            #pragma unroll
            for (int u = 0; u < 4; ++u) {
                const size_t cb = (size_t)(k[u] & 0x1FFFFu) * D;
                #pragma unroll
                for (int q = 0; q < 4; ++q)
                    sv[u][q] = S[cb + q * 64 + lane];
            }
            #pragma unroll
            for (int u = 0; u < 4; ++u) {
                float* arow = accum + (k[u] >> 17) * D;
                #pragma unroll
                for (int q = 0; q < 4; ++q)
                    atomicAdd(&arow[q * 64 + lane], vv[u] * bf2f(sv[u][q]));
            }
        }
        for (; j < n; ++j) {
            const u32 ku = __shfl(key, j);
            const float vu = __shfl(v, j);
            const size_t cb = (size_t)(ku & 0x1FFFFu) * D;
            float* arow = accum + (ku >> 17) * D;
            #pragma unroll
            for (int q = 0; q < 4; ++q)
                atomicAdd(&arow[q * 64 + lane], vu * bf2f(S[cb + q * 64 + lane]));
        }
    }

    __syncthreads();
    const float4* b4v = (const float4*)bias;
    float4* o4 = (float4*)(out + (size_t)bkt * RPB * D);
    #pragma unroll
    for (int i = 0; i < RPB * D / 4 / 256; ++i) {
        const int idx = i * 256 + tid;
        float4 t = a4[idx];
        const float4 bb = b4v[idx & 63];
        t.x += bb.x; t.y += bb.y; t.z += bb.z; t.w += bb.w;
        o4[idx] = t;
    }
}

extern "C" void kernel_launch(void* const* d_in, const int* in_sizes, int n_in,
                              void* d_out, int out_size, void* d_ws, size_t ws_size,
                              hipStream_t stream) {
    const float* X    = (const float*)d_in[0];
    const int*   row  = (const int*)d_in[1];
    const int*   col  = (const int*)d_in[2];
    const float* val  = (const float*)d_in[3];
    const float* W    = (const float*)d_in[4];
    const float* bias = (const float*)d_in[5];
    float* out = (float*)d_out;

    // workspace layout (~77 MB; ~100 MB proven available in round 1)
    char* ws = (char*)d_ws;
    u16*   Sx     = (u16*)ws;                     // 51,200,000 B
    int*   starts = (int*)(ws + 51200000);        //     50,048 B (12501 ints, padded)
    int*   cnt    = (int*)(ws + 51250048);        //     50,048 B (cursor after scan)
    uint2* pce    = (uint2*)(ws + 51300096);      // 25,600,000 B (8-aligned)
    u16*   Wf     = (u16*)(ws + 76900096);        //    131,072 B (16-aligned)

    // 1) prep: zero bucket counters + W -> bf16 B-fragment layout
    prep_kernel<<<ZERO_BLOCKS + WSH_BLOCKS, 256, 0, stream>>>(W, Wf, cnt);

    // 2) fused GEMM + bucket histogram
    gemm_hist_kernel<<<GEMM_BLOCKS + HIST_BLOCKS, 256, 0, stream>>>(X, Wf, Sx, row, cnt);

    // 3) scan bucket counts -> starts (and cursor init)
    bucketscan_kernel<<<1, 1024, 0, stream>>>(cnt, starts);

    // 4) placement into bucket segments
    place_kernel<<<N_EDGES / 256, 256, 0, stream>>>(row, col, val, cnt, pce);

    // 5) reduce: block per bucket, LDS accumulate, single coalesced writeout
    reduce_kernel<<<NBUCKET, 256, 0, stream>>>(Sx, starts, pce, bias, out);
}